// Round 1
// baseline (1814.522 us; speedup 1.0000x reference)
//
#include <hip/hip_runtime.h>
#include <math.h>

// GCN 2-layer:
//   h   = relu(segsum(feat[src]) @ W1 + b1)
//   out = softmax(segsum(h[src]) @ W2 + b2)
// Optimization: segsum and @W2 commute, so project h->p=h@W2 (64->16) BEFORE
// the second aggregation: out = softmax(segsum(p[src]) + b2). 4x less edge
// traffic in layer 2.

// ---------- scatter 1: agg1[dst] += feat[src], F=64, float4 per thread ----------
__global__ void scatter1_kernel(const float4* __restrict__ feat4,
                                const int* __restrict__ src,
                                const int* __restrict__ dst,
                                float* __restrict__ agg1, long total) {
    long i = (long)blockIdx.x * blockDim.x + threadIdx.x;
    long stride = (long)gridDim.x * blockDim.x;
    for (; i < total; i += stride) {
        int e = (int)(i >> 4);
        int q = (int)(i & 15);
        int s = src[e];
        int d = dst[e];
        float4 v = feat4[(long)s * 16 + q];
        float* base = agg1 + (long)d * 64 + q * 4;
        atomicAdd(base + 0, v.x);
        atomicAdd(base + 1, v.y);
        atomicAdd(base + 2, v.z);
        atomicAdd(base + 3, v.w);
    }
}

// ---------- dense 1: h = relu(agg1 @ W1 + b1), in-place over agg1 ----------
// Thread (n,j) with j = tid&63: one WAVE covers exactly one row (64 lanes),
// so all row loads (lockstep, program-order before the store) complete before
// any lane overwrites the row. In-place is safe.
__global__ void dense1_kernel(float* __restrict__ agg1,
                              const float* __restrict__ W1,
                              const float* __restrict__ b1, int n_nodes) {
    int i = blockIdx.x * blockDim.x + threadIdx.x;
    int n = i >> 6;
    int j = i & 63;
    if (n >= n_nodes) return;
    const float* row = agg1 + (long)n * 64;
    float sum = b1[j];
#pragma unroll
    for (int k = 0; k < 64; ++k) {
        sum = fmaf(row[k], W1[k * 64 + j], sum);
    }
    agg1[(long)n * 64 + j] = fmaxf(sum, 0.0f);
}

// ---------- dense 2: p = h @ W2  ([N,64] x [64,16] -> [N,16]) ----------
__global__ void dense2_kernel(const float* __restrict__ h,
                              const float* __restrict__ W2,
                              float* __restrict__ p, int n_nodes) {
    int i = blockIdx.x * blockDim.x + threadIdx.x;
    int n = i >> 4;
    int c = i & 15;
    if (n >= n_nodes) return;
    const float* row = h + (long)n * 64;
    float sum = 0.0f;
#pragma unroll
    for (int j = 0; j < 64; ++j) {
        sum = fmaf(row[j], W2[j * 16 + c], sum);
    }
    p[(long)n * 16 + c] = sum;
}

// ---------- scatter 2: out[dst] += p[src], F=16, float4 per thread ----------
__global__ void scatter2_kernel(const float4* __restrict__ p4,
                                const int* __restrict__ src,
                                const int* __restrict__ dst,
                                float* __restrict__ agg2, long total) {
    long i = (long)blockIdx.x * blockDim.x + threadIdx.x;
    long stride = (long)gridDim.x * blockDim.x;
    for (; i < total; i += stride) {
        int e = (int)(i >> 2);
        int q = (int)(i & 3);
        int s = src[e];
        int d = dst[e];
        float4 v = p4[(long)s * 4 + q];
        float* base = agg2 + (long)d * 16 + q * 4;
        atomicAdd(base + 0, v.x);
        atomicAdd(base + 1, v.y);
        atomicAdd(base + 2, v.z);
        atomicAdd(base + 3, v.w);
    }
}

// ---------- softmax over 16 classes (+b2), in-place on out ----------
__global__ void softmax_kernel(float* __restrict__ out,
                               const float* __restrict__ b2, int n_nodes) {
    int n = blockIdx.x * blockDim.x + threadIdx.x;
    if (n >= n_nodes) return;
    float v[16];
    float4* row4 = (float4*)(out + (long)n * 16);
#pragma unroll
    for (int q = 0; q < 4; ++q) {
        float4 t = row4[q];
        v[q * 4 + 0] = t.x + b2[q * 4 + 0];
        v[q * 4 + 1] = t.y + b2[q * 4 + 1];
        v[q * 4 + 2] = t.z + b2[q * 4 + 2];
        v[q * 4 + 3] = t.w + b2[q * 4 + 3];
    }
    float m = v[0];
#pragma unroll
    for (int c = 1; c < 16; ++c) m = fmaxf(m, v[c]);
    float s = 0.0f;
#pragma unroll
    for (int c = 0; c < 16; ++c) {
        v[c] = __expf(v[c] - m);
        s += v[c];
    }
    float inv = 1.0f / s;
#pragma unroll
    for (int q = 0; q < 4; ++q) {
        float4 t;
        t.x = v[q * 4 + 0] * inv;
        t.y = v[q * 4 + 1] * inv;
        t.z = v[q * 4 + 2] * inv;
        t.w = v[q * 4 + 3] * inv;
        row4[q] = t;
    }
}

extern "C" void kernel_launch(void* const* d_in, const int* in_sizes, int n_in,
                              void* d_out, int out_size, void* d_ws, size_t ws_size,
                              hipStream_t stream) {
    const float* feat = (const float*)d_in[0];
    const float* W1   = (const float*)d_in[1];
    const float* b1   = (const float*)d_in[2];
    const float* W2   = (const float*)d_in[3];
    const float* b2   = (const float*)d_in[4];
    const int*   src  = (const int*)d_in[5];
    const int*   dst  = (const int*)d_in[6];

    int n_nodes = in_sizes[0] / 64;
    int n_edges = in_sizes[5];

    float* agg1 = (float*)d_ws;                       // [N,64], then h in-place
    float* p    = agg1 + (size_t)n_nodes * 64;        // [N,16]
    float* out  = (float*)d_out;                      // [N,16] agg2, then softmax

    // Atomics accumulate -> must zero every call (harness doesn't re-poison).
    hipMemsetAsync(agg1, 0, (size_t)n_nodes * 64 * sizeof(float), stream);
    hipMemsetAsync(out,  0, (size_t)n_nodes * 16 * sizeof(float), stream);

    long t1 = (long)n_edges * 16;  // (edge, float4-quad) pairs, F=64
    scatter1_kernel<<<2048, 256, 0, stream>>>((const float4*)feat, src, dst, agg1, t1);

    dense1_kernel<<<(n_nodes * 64 + 255) / 256, 256, 0, stream>>>(agg1, W1, b1, n_nodes);
    dense2_kernel<<<(n_nodes * 16 + 255) / 256, 256, 0, stream>>>(agg1, W2, p, n_nodes);

    long t2 = (long)n_edges * 4;   // (edge, float4-quad) pairs, F=16
    scatter2_kernel<<<2048, 256, 0, stream>>>((const float4*)p, src, dst, out, t2);

    softmax_kernel<<<(n_nodes + 255) / 256, 256, 0, stream>>>(out, b2, n_nodes);
}

// Round 2
// 473.090 us; speedup vs baseline: 3.8355x; 3.8355x over previous
//
#include <hip/hip_runtime.h>
#include <math.h>

// GCN 2-layer, pull-based:
//   CSR-by-dst (counting sort) -> per-node gather-sum (no float atomics)
//   layer1 fused: gather + relu(agg@W1+b1) + @W2  -> p[N,16]
//   layer2 fused: gather(p) + b2 + softmax        -> out[N,16]
// Algebraic: segsum and @W2 commute, so project 64->16 before 2nd aggregation.

#define SCAN_B 1024

__global__ void hist_kernel(const int* __restrict__ dst, int* __restrict__ counts, int E) {
    int e = blockIdx.x * blockDim.x + threadIdx.x;
    if (e < E) atomicAdd(&counts[dst[e]], 1);
}

__global__ void scan_phaseA(const int* __restrict__ counts, int* __restrict__ excl,
                            int* __restrict__ blocksums, int n) {
    __shared__ int lds[SCAN_B];
    int tid = threadIdx.x;
    int i = blockIdx.x * SCAN_B + tid;
    int v = (i < n) ? counts[i] : 0;
    lds[tid] = v;
    __syncthreads();
    for (int off = 1; off < SCAN_B; off <<= 1) {
        int t = (tid >= off) ? lds[tid - off] : 0;
        __syncthreads();
        lds[tid] += t;
        __syncthreads();
    }
    if (i < n) excl[i] = lds[tid] - v;                 // exclusive within chunk
    if (tid == SCAN_B - 1) blocksums[blockIdx.x] = lds[SCAN_B - 1];
}

__global__ void scan_phaseB(int* blocksums, int nb) {
    __shared__ int lds[SCAN_B];
    int tid = threadIdx.x;
    int v = (tid < nb) ? blocksums[tid] : 0;
    lds[tid] = v;
    __syncthreads();
    for (int off = 1; off < SCAN_B; off <<= 1) {
        int t = (tid >= off) ? lds[tid - off] : 0;
        __syncthreads();
        lds[tid] += t;
        __syncthreads();
    }
    if (tid < nb) blocksums[tid] = lds[tid] - v;       // exclusive chunk offsets
}

__global__ void scan_phaseC(int* __restrict__ offs, const int* __restrict__ blocksums,
                            int* __restrict__ cursor, int n, int E) {
    int i = blockIdx.x * blockDim.x + threadIdx.x;
    if (i < n) {
        int o = offs[i] + blocksums[i / SCAN_B];
        offs[i] = o;
        cursor[i] = o;
    } else if (i == n) {
        offs[n] = E;
    }
}

__global__ void fill_kernel(const int* __restrict__ src, const int* __restrict__ dst,
                            int* __restrict__ cursor, int* __restrict__ ssort, int E) {
    int e = blockIdx.x * blockDim.x + threadIdx.x;
    if (e < E) {
        int pos = atomicAdd(&cursor[dst[e]], 1);
        ssort[pos] = src[e];
    }
}

// ---------- layer 1: wave per node. gather-sum + dense1(relu) + dense2 ----------
__global__ __launch_bounds__(256) void layer1_kernel(
    const float* __restrict__ feat, const int* __restrict__ offs,
    const int* __restrict__ ssort, const float* __restrict__ W1,
    const float* __restrict__ b1, const float* __restrict__ W2,
    float* __restrict__ p, int n_nodes)
{
    __shared__ float lds[4][64];
    int lane = threadIdx.x & 63;
    int w = threadIdx.x >> 6;
    int node = blockIdx.x * 4 + w;
    bool active = node < n_nodes;
    int beg = 0, end = 0;
    if (active) { beg = offs[node]; end = offs[node + 1]; }
    // gather-sum: lane = feature column; per edge a coalesced 256B row read
    float acc = 0.f;
    for (int k = beg; k < end; ++k) {
        int s = ssort[k];
        acc += feat[(size_t)s * 64 + lane];
    }
    lds[w][lane] = acc;
    __syncthreads();
    // dense1: h[lane] = relu(b1 + sum_k agg[k] * W1[k,lane]); LDS reads broadcast
    float h = b1[lane];
    const float4* row4 = (const float4*)lds[w];
#pragma unroll
    for (int k4 = 0; k4 < 16; ++k4) {
        float4 a = row4[k4];
        h = fmaf(a.x, W1[(k4 * 4 + 0) * 64 + lane], h);
        h = fmaf(a.y, W1[(k4 * 4 + 1) * 64 + lane], h);
        h = fmaf(a.z, W1[(k4 * 4 + 2) * 64 + lane], h);
        h = fmaf(a.w, W1[(k4 * 4 + 3) * 64 + lane], h);
    }
    h = fmaxf(h, 0.f);
    __syncthreads();                  // all reads of agg done before overwrite
    lds[w][lane] = h;
    __syncthreads();
    // dense2: p[node, c] = sum_j h[j] * W2[j, c]; 16 lanes
    if (active && lane < 16) {
        float s = 0.f;
        const float4* hr = (const float4*)lds[w];
#pragma unroll
        for (int j4 = 0; j4 < 16; ++j4) {
            float4 a = hr[j4];
            s = fmaf(a.x, W2[(j4 * 4 + 0) * 16 + lane], s);
            s = fmaf(a.y, W2[(j4 * 4 + 1) * 16 + lane], s);
            s = fmaf(a.z, W2[(j4 * 4 + 2) * 16 + lane], s);
            s = fmaf(a.w, W2[(j4 * 4 + 3) * 16 + lane], s);
        }
        p[(size_t)node * 16 + lane] = s;
    }
}

// ---------- layer 2: wave per node. gather-sum(p) + b2 + softmax ----------
__global__ __launch_bounds__(256) void layer2_kernel(
    const float* __restrict__ p, const int* __restrict__ offs,
    const int* __restrict__ ssort, const float* __restrict__ b2,
    float* __restrict__ out, int n_nodes)
{
    int lane = threadIdx.x & 63;
    int w = threadIdx.x >> 6;
    int node = blockIdx.x * 4 + w;
    if (node >= n_nodes) return;      // no barriers below
    int kq = lane >> 4;               // edge slot 0..3
    int j = lane & 15;                // class column
    int beg = offs[node], end = offs[node + 1];
    float acc = 0.f;
    for (int k = beg + kq; k < end; k += 4) {
        int s = ssort[k];
        acc += p[(size_t)s * 16 + j];
    }
    // reduce the 4 edge slots -> every lane holds column total
    acc += __shfl_xor(acc, 16, 64);
    acc += __shfl_xor(acc, 32, 64);
    float v = acc + b2[j];
    // softmax over the 16-lane class group
    float m = v;
    m = fmaxf(m, __shfl_xor(m, 1, 64));
    m = fmaxf(m, __shfl_xor(m, 2, 64));
    m = fmaxf(m, __shfl_xor(m, 4, 64));
    m = fmaxf(m, __shfl_xor(m, 8, 64));
    float e = __expf(v - m);
    float s = e;
    s += __shfl_xor(s, 1, 64);
    s += __shfl_xor(s, 2, 64);
    s += __shfl_xor(s, 4, 64);
    s += __shfl_xor(s, 8, 64);
    if (lane < 16) out[(size_t)node * 16 + lane] = e / s;
}

extern "C" void kernel_launch(void* const* d_in, const int* in_sizes, int n_in,
                              void* d_out, int out_size, void* d_ws, size_t ws_size,
                              hipStream_t stream) {
    const float* feat = (const float*)d_in[0];
    const float* W1   = (const float*)d_in[1];
    const float* b1   = (const float*)d_in[2];
    const float* W2   = (const float*)d_in[3];
    const float* b2   = (const float*)d_in[4];
    const int*   src  = (const int*)d_in[5];
    const int*   dst  = (const int*)d_in[6];

    int N = in_sizes[0] / 64;
    int E = in_sizes[5];

    float* p        = (float*)d_ws;                    // N*16 floats
    int*   counts   = (int*)(p + (size_t)N * 16);      // N
    int*   offs     = counts + N;                      // N+1
    int*   cursor   = offs + N + 1;                    // N
    int*   bsums    = cursor + N;                      // SCAN_B slots (nb<=98)
    int*   ssort    = bsums + SCAN_B;                  // E
    float* out      = (float*)d_out;

    int nb = (N + SCAN_B - 1) / SCAN_B;

    hipMemsetAsync(counts, 0, (size_t)N * sizeof(int), stream);

    hist_kernel<<<(E + 255) / 256, 256, 0, stream>>>(dst, counts, E);
    scan_phaseA<<<nb, SCAN_B, 0, stream>>>(counts, offs, bsums, N);
    scan_phaseB<<<1, SCAN_B, 0, stream>>>(bsums, nb);
    scan_phaseC<<<(N + 1 + 255) / 256, 256, 0, stream>>>(offs, bsums, cursor, N, E);
    fill_kernel<<<(E + 255) / 256, 256, 0, stream>>>(src, dst, cursor, ssort, E);

    layer1_kernel<<<(N + 3) / 4, 256, 0, stream>>>(feat, offs, ssort, W1, b1, W2, p, N);
    layer2_kernel<<<(N + 3) / 4, 256, 0, stream>>>(p, offs, ssort, b2, out, N);
}

// Round 3
// 390.535 us; speedup vs baseline: 4.6462x; 1.2114x over previous
//
#include <hip/hip_runtime.h>
#include <math.h>

// GCN 2-layer, pull-based:
//   CSR-by-dst (counting sort) -> per-node gather-sum (no float atomics)
//   layer1 fused: gather + relu(agg@W1+b1) + @W2  -> p[N,16]
//   layer2 fused: gather(p) + b2 + softmax        -> out[N,16]
// R2: 8-way MLP unroll in both gather loops (latency-bound per rocprof:
//     VALUBusy 19%, HBM 10%, serial edge loop was 1 outstanding load/wave).

#define SCAN_B 1024

__global__ void hist_kernel(const int* __restrict__ dst, int* __restrict__ counts, int E) {
    int e = blockIdx.x * blockDim.x + threadIdx.x;
    if (e < E) atomicAdd(&counts[dst[e]], 1);
}

__global__ void scan_phaseA(const int* __restrict__ counts, int* __restrict__ excl,
                            int* __restrict__ blocksums, int n) {
    __shared__ int lds[SCAN_B];
    int tid = threadIdx.x;
    int i = blockIdx.x * SCAN_B + tid;
    int v = (i < n) ? counts[i] : 0;
    lds[tid] = v;
    __syncthreads();
    for (int off = 1; off < SCAN_B; off <<= 1) {
        int t = (tid >= off) ? lds[tid - off] : 0;
        __syncthreads();
        lds[tid] += t;
        __syncthreads();
    }
    if (i < n) excl[i] = lds[tid] - v;                 // exclusive within chunk
    if (tid == SCAN_B - 1) blocksums[blockIdx.x] = lds[SCAN_B - 1];
}

__global__ void scan_phaseB(int* blocksums, int nb) {
    __shared__ int lds[SCAN_B];
    int tid = threadIdx.x;
    int v = (tid < nb) ? blocksums[tid] : 0;
    lds[tid] = v;
    __syncthreads();
    for (int off = 1; off < SCAN_B; off <<= 1) {
        int t = (tid >= off) ? lds[tid - off] : 0;
        __syncthreads();
        lds[tid] += t;
        __syncthreads();
    }
    if (tid < nb) blocksums[tid] = lds[tid] - v;       // exclusive chunk offsets
}

__global__ void scan_phaseC(int* __restrict__ offs, const int* __restrict__ blocksums,
                            int* __restrict__ cursor, int n, int E) {
    int i = blockIdx.x * blockDim.x + threadIdx.x;
    if (i < n) {
        int o = offs[i] + blocksums[i / SCAN_B];
        offs[i] = o;
        cursor[i] = o;
    } else if (i == n) {
        offs[n] = E;
    }
}

__global__ void fill_kernel(const int* __restrict__ src, const int* __restrict__ dst,
                            int* __restrict__ cursor, int* __restrict__ ssort, int E) {
    int e = blockIdx.x * blockDim.x + threadIdx.x;
    if (e < E) {
        int pos = atomicAdd(&cursor[dst[e]], 1);
        ssort[pos] = src[e];
    }
}

// ---------- layer 1: wave per node. gather-sum + dense1(relu) + dense2 ----------
__global__ __launch_bounds__(256) void layer1_kernel(
    const float* __restrict__ feat, const int* __restrict__ offs,
    const int* __restrict__ ssort, const float* __restrict__ W1,
    const float* __restrict__ b1, const float* __restrict__ W2,
    float* __restrict__ p, int n_nodes)
{
    __shared__ float lds[4][64];
    int lane = threadIdx.x & 63;
    int w = threadIdx.x >> 6;
    int node = blockIdx.x * 4 + w;
    bool active = node < n_nodes;
    int beg = 0, end = 0;
    if (active) { beg = offs[node]; end = offs[node + 1]; }
    // gather-sum: lane = feature column. 8-way unroll -> 8 outstanding 256B
    // row reads per wave (was 1: latency-bound).
    float acc = 0.f;
    int k = beg;
    for (; k + 8 <= end; k += 8) {
        int s0 = ssort[k + 0], s1 = ssort[k + 1], s2 = ssort[k + 2], s3 = ssort[k + 3];
        int s4 = ssort[k + 4], s5 = ssort[k + 5], s6 = ssort[k + 6], s7 = ssort[k + 7];
        float a0 = feat[(size_t)s0 * 64 + lane];
        float a1 = feat[(size_t)s1 * 64 + lane];
        float a2 = feat[(size_t)s2 * 64 + lane];
        float a3 = feat[(size_t)s3 * 64 + lane];
        float a4 = feat[(size_t)s4 * 64 + lane];
        float a5 = feat[(size_t)s5 * 64 + lane];
        float a6 = feat[(size_t)s6 * 64 + lane];
        float a7 = feat[(size_t)s7 * 64 + lane];
        acc += ((a0 + a1) + (a2 + a3)) + ((a4 + a5) + (a6 + a7));
    }
    for (; k < end; ++k) {
        acc += feat[(size_t)ssort[k] * 64 + lane];
    }
    lds[w][lane] = acc;
    __syncthreads();
    // dense1: h[lane] = relu(b1 + sum_k agg[k] * W1[k,lane]); LDS reads broadcast
    float h = b1[lane];
    const float4* row4 = (const float4*)lds[w];
#pragma unroll
    for (int k4 = 0; k4 < 16; ++k4) {
        float4 a = row4[k4];
        h = fmaf(a.x, W1[(k4 * 4 + 0) * 64 + lane], h);
        h = fmaf(a.y, W1[(k4 * 4 + 1) * 64 + lane], h);
        h = fmaf(a.z, W1[(k4 * 4 + 2) * 64 + lane], h);
        h = fmaf(a.w, W1[(k4 * 4 + 3) * 64 + lane], h);
    }
    h = fmaxf(h, 0.f);
    __syncthreads();                  // all reads of agg done before overwrite
    lds[w][lane] = h;
    __syncthreads();
    // dense2: p[node, c] = sum_j h[j] * W2[j, c]; 16 lanes
    if (active && lane < 16) {
        float s = 0.f;
        const float4* hr = (const float4*)lds[w];
#pragma unroll
        for (int j4 = 0; j4 < 16; ++j4) {
            float4 a = hr[j4];
            s = fmaf(a.x, W2[(j4 * 4 + 0) * 16 + lane], s);
            s = fmaf(a.y, W2[(j4 * 4 + 1) * 16 + lane], s);
            s = fmaf(a.z, W2[(j4 * 4 + 2) * 16 + lane], s);
            s = fmaf(a.w, W2[(j4 * 4 + 3) * 16 + lane], s);
        }
        p[(size_t)node * 16 + lane] = s;
    }
}

// ---------- layer 2: wave per node. gather-sum(p) + b2 + softmax ----------
__global__ __launch_bounds__(256) void layer2_kernel(
    const float* __restrict__ p, const int* __restrict__ offs,
    const int* __restrict__ ssort, const float* __restrict__ b2,
    float* __restrict__ out, int n_nodes)
{
    int lane = threadIdx.x & 63;
    int w = threadIdx.x >> 6;
    int node = blockIdx.x * 4 + w;
    if (node >= n_nodes) return;      // no barriers below
    int kq = lane >> 4;               // edge slot 0..3
    int j = lane & 15;                // class column
    int beg = offs[node], end = offs[node + 1];
    // 4 subgroups x 2-way unroll = 8 outstanding row reads per wave
    float acc = 0.f;
    int k = beg + kq;
    for (; k + 8 <= end + kq; k += 8) {
        int s0 = ssort[k];
        int s1 = ssort[k + 4];
        acc += p[(size_t)s0 * 16 + j];
        acc += p[(size_t)s1 * 16 + j];
    }
    for (; k < end; k += 4) {
        acc += p[(size_t)ssort[k] * 16 + j];
    }
    // reduce the 4 edge slots -> every lane holds column total
    acc += __shfl_xor(acc, 16, 64);
    acc += __shfl_xor(acc, 32, 64);
    float v = acc + b2[j];
    // softmax over the 16-lane class group
    float m = v;
    m = fmaxf(m, __shfl_xor(m, 1, 64));
    m = fmaxf(m, __shfl_xor(m, 2, 64));
    m = fmaxf(m, __shfl_xor(m, 4, 64));
    m = fmaxf(m, __shfl_xor(m, 8, 64));
    float e = __expf(v - m);
    float s = e;
    s += __shfl_xor(s, 1, 64);
    s += __shfl_xor(s, 2, 64);
    s += __shfl_xor(s, 4, 64);
    s += __shfl_xor(s, 8, 64);
    if (lane < 16) out[(size_t)node * 16 + lane] = e / s;
}

extern "C" void kernel_launch(void* const* d_in, const int* in_sizes, int n_in,
                              void* d_out, int out_size, void* d_ws, size_t ws_size,
                              hipStream_t stream) {
    const float* feat = (const float*)d_in[0];
    const float* W1   = (const float*)d_in[1];
    const float* b1   = (const float*)d_in[2];
    const float* W2   = (const float*)d_in[3];
    const float* b2   = (const float*)d_in[4];
    const int*   src  = (const int*)d_in[5];
    const int*   dst  = (const int*)d_in[6];

    int N = in_sizes[0] / 64;
    int E = in_sizes[5];

    float* p        = (float*)d_ws;                    // N*16 floats
    int*   counts   = (int*)(p + (size_t)N * 16);      // N
    int*   offs     = counts + N;                      // N+1
    int*   cursor   = offs + N + 1;                    // N
    int*   bsums    = cursor + N;                      // SCAN_B slots (nb<=98)
    int*   ssort    = bsums + SCAN_B;                  // E
    float* out      = (float*)d_out;

    int nb = (N + SCAN_B - 1) / SCAN_B;

    hipMemsetAsync(counts, 0, (size_t)N * sizeof(int), stream);

    hist_kernel<<<(E + 255) / 256, 256, 0, stream>>>(dst, counts, E);
    scan_phaseA<<<nb, SCAN_B, 0, stream>>>(counts, offs, bsums, N);
    scan_phaseB<<<1, SCAN_B, 0, stream>>>(bsums, nb);
    scan_phaseC<<<(N + 1 + 255) / 256, 256, 0, stream>>>(offs, bsums, cursor, N, E);
    fill_kernel<<<(E + 255) / 256, 256, 0, stream>>>(src, dst, cursor, ssort, E);

    layer1_kernel<<<(N + 3) / 4, 256, 0, stream>>>(feat, offs, ssort, W1, b1, W2, p, N);
    layer2_kernel<<<(N + 3) / 4, 256, 0, stream>>>(p, offs, ssort, b2, out, N);
}

// Round 4
// 373.973 us; speedup vs baseline: 4.8520x; 1.0443x over previous
//
#include <hip/hip_runtime.h>
#include <math.h>

// GCN 2-layer, pull-based (CSR by dst, counting sort), no float atomics.
//   layer1 fused: gather(bf16 feat) + relu(agg@W1+b1) + @W2 -> p[N,16] f32
//   layer2 fused: gather(p, float2/lane, 8 edges/instr) + b2 + softmax -> out
// R3: gather was throughput-bound on random 256B rows (FETCH 177MB vs 410MB
//     logical, 1.2TB/s effective). Halve bytes with a precomputed bf16
//     feature table; 2 edges per load instr (half-wave each).

#define SCAN_B 1024

__device__ __forceinline__ unsigned short f2bf(float x) {
    unsigned u = __float_as_uint(x);
    unsigned r = (u + 0x7fff + ((u >> 16) & 1)) >> 16;   // RNE
    return (unsigned short)r;
}

__global__ void tobf16_kernel(const float2* __restrict__ f, unsigned* __restrict__ g, long n) {
    long i = (long)blockIdx.x * blockDim.x + threadIdx.x;
    if (i < n) {
        float2 v = f[i];
        g[i] = (unsigned)f2bf(v.x) | ((unsigned)f2bf(v.y) << 16);
    }
}

__global__ void hist_kernel(const int* __restrict__ dst, int* __restrict__ counts, int E) {
    int e = blockIdx.x * blockDim.x + threadIdx.x;
    if (e < E) atomicAdd(&counts[dst[e]], 1);
}

__global__ void scan_phaseA(const int* __restrict__ counts, int* __restrict__ excl,
                            int* __restrict__ blocksums, int n) {
    __shared__ int lds[SCAN_B];
    int tid = threadIdx.x;
    int i = blockIdx.x * SCAN_B + tid;
    int v = (i < n) ? counts[i] : 0;
    lds[tid] = v;
    __syncthreads();
    for (int off = 1; off < SCAN_B; off <<= 1) {
        int t = (tid >= off) ? lds[tid - off] : 0;
        __syncthreads();
        lds[tid] += t;
        __syncthreads();
    }
    if (i < n) excl[i] = lds[tid] - v;
    if (tid == SCAN_B - 1) blocksums[blockIdx.x] = lds[SCAN_B - 1];
}

__global__ void scan_phaseB(int* blocksums, int nb) {
    __shared__ int lds[SCAN_B];
    int tid = threadIdx.x;
    int v = (tid < nb) ? blocksums[tid] : 0;
    lds[tid] = v;
    __syncthreads();
    for (int off = 1; off < SCAN_B; off <<= 1) {
        int t = (tid >= off) ? lds[tid - off] : 0;
        __syncthreads();
        lds[tid] += t;
        __syncthreads();
    }
    if (tid < nb) blocksums[tid] = lds[tid] - v;
}

__global__ void scan_phaseC(int* __restrict__ offs, const int* __restrict__ blocksums,
                            int* __restrict__ cursor, int n, int E) {
    int i = blockIdx.x * blockDim.x + threadIdx.x;
    if (i < n) {
        int o = offs[i] + blocksums[i / SCAN_B];
        offs[i] = o;
        cursor[i] = o;
    } else if (i == n) {
        offs[n] = E;
    }
}

__global__ void fill_kernel(const int* __restrict__ src, const int* __restrict__ dst,
                            int* __restrict__ cursor, int* __restrict__ ssort, int E) {
    int e = blockIdx.x * blockDim.x + threadIdx.x;
    if (e < E) {
        int pos = atomicAdd(&cursor[dst[e]], 1);
        ssort[pos] = src[e];
    }
}

// ---------- layer 1 (bf16 gather): wave/node; half-wave per edge ----------
__global__ __launch_bounds__(256) void layer1_bf16_kernel(
    const unsigned* __restrict__ gbf,      // [N][32] u32 = 2 packed bf16 cols
    const int* __restrict__ offs, const int* __restrict__ ssort,
    const float* __restrict__ W1, const float* __restrict__ b1,
    const float* __restrict__ W2, float* __restrict__ p, int n_nodes)
{
    __shared__ float lds[4][64];
    int lane = threadIdx.x & 63;
    int w = threadIdx.x >> 6;
    int node = blockIdx.x * 4 + w;
    bool active = node < n_nodes;
    int beg = 0, end = 0;
    if (active) { beg = offs[node]; end = offs[node + 1]; }
    int half = lane >> 5;     // which edge of the pair
    int sl = lane & 31;       // column pair 0..31 -> cols 2sl, 2sl+1
    float ax = 0.f, ay = 0.f;
    int k = beg + half;
    // 4 pairs unrolled -> 8 edges in flight per wave, 128B/edge
    for (; k + 6 < end; k += 8) {
        int s0 = ssort[k], s1 = ssort[k + 2], s2 = ssort[k + 4], s3 = ssort[k + 6];
        unsigned u0 = gbf[(size_t)s0 * 32 + sl];
        unsigned u1 = gbf[(size_t)s1 * 32 + sl];
        unsigned u2 = gbf[(size_t)s2 * 32 + sl];
        unsigned u3 = gbf[(size_t)s3 * 32 + sl];
        ax += (__uint_as_float(u0 << 16) + __uint_as_float(u1 << 16))
            + (__uint_as_float(u2 << 16) + __uint_as_float(u3 << 16));
        ay += (__uint_as_float(u0 & 0xffff0000u) + __uint_as_float(u1 & 0xffff0000u))
            + (__uint_as_float(u2 & 0xffff0000u) + __uint_as_float(u3 & 0xffff0000u));
    }
    for (; k < end; k += 2) {
        unsigned u = gbf[(size_t)ssort[k] * 32 + sl];
        ax += __uint_as_float(u << 16);
        ay += __uint_as_float(u & 0xffff0000u);
    }
    ax += __shfl_xor(ax, 32, 64);
    ay += __shfl_xor(ay, 32, 64);
    if (half == 0) {
        lds[w][2 * sl]     = ax;
        lds[w][2 * sl + 1] = ay;
    }
    __syncthreads();
    // dense1: h[lane] = relu(b1 + sum_k agg[k]*W1[k,lane])
    float h = b1[lane];
    const float4* row4 = (const float4*)lds[w];
#pragma unroll
    for (int k4 = 0; k4 < 16; ++k4) {
        float4 a = row4[k4];
        h = fmaf(a.x, W1[(k4 * 4 + 0) * 64 + lane], h);
        h = fmaf(a.y, W1[(k4 * 4 + 1) * 64 + lane], h);
        h = fmaf(a.z, W1[(k4 * 4 + 2) * 64 + lane], h);
        h = fmaf(a.w, W1[(k4 * 4 + 3) * 64 + lane], h);
    }
    h = fmaxf(h, 0.f);
    __syncthreads();
    lds[w][lane] = h;
    __syncthreads();
    if (active && lane < 16) {
        float s = 0.f;
        const float4* hr = (const float4*)lds[w];
#pragma unroll
        for (int j4 = 0; j4 < 16; ++j4) {
            float4 a = hr[j4];
            s = fmaf(a.x, W2[(j4 * 4 + 0) * 16 + lane], s);
            s = fmaf(a.y, W2[(j4 * 4 + 1) * 16 + lane], s);
            s = fmaf(a.z, W2[(j4 * 4 + 2) * 16 + lane], s);
            s = fmaf(a.w, W2[(j4 * 4 + 3) * 16 + lane], s);
        }
        p[(size_t)node * 16 + lane] = s;
    }
}

// ---------- layer 1 fallback (f32 gather), R2 version ----------
__global__ __launch_bounds__(256) void layer1_f32_kernel(
    const float* __restrict__ feat, const int* __restrict__ offs,
    const int* __restrict__ ssort, const float* __restrict__ W1,
    const float* __restrict__ b1, const float* __restrict__ W2,
    float* __restrict__ p, int n_nodes)
{
    __shared__ float lds[4][64];
    int lane = threadIdx.x & 63;
    int w = threadIdx.x >> 6;
    int node = blockIdx.x * 4 + w;
    bool active = node < n_nodes;
    int beg = 0, end = 0;
    if (active) { beg = offs[node]; end = offs[node + 1]; }
    float acc = 0.f;
    int k = beg;
    for (; k + 8 <= end; k += 8) {
        int s0 = ssort[k + 0], s1 = ssort[k + 1], s2 = ssort[k + 2], s3 = ssort[k + 3];
        int s4 = ssort[k + 4], s5 = ssort[k + 5], s6 = ssort[k + 6], s7 = ssort[k + 7];
        float a0 = feat[(size_t)s0 * 64 + lane];
        float a1 = feat[(size_t)s1 * 64 + lane];
        float a2 = feat[(size_t)s2 * 64 + lane];
        float a3 = feat[(size_t)s3 * 64 + lane];
        float a4 = feat[(size_t)s4 * 64 + lane];
        float a5 = feat[(size_t)s5 * 64 + lane];
        float a6 = feat[(size_t)s6 * 64 + lane];
        float a7 = feat[(size_t)s7 * 64 + lane];
        acc += ((a0 + a1) + (a2 + a3)) + ((a4 + a5) + (a6 + a7));
    }
    for (; k < end; ++k) acc += feat[(size_t)ssort[k] * 64 + lane];
    lds[w][lane] = acc;
    __syncthreads();
    float h = b1[lane];
    const float4* row4 = (const float4*)lds[w];
#pragma unroll
    for (int k4 = 0; k4 < 16; ++k4) {
        float4 a = row4[k4];
        h = fmaf(a.x, W1[(k4 * 4 + 0) * 64 + lane], h);
        h = fmaf(a.y, W1[(k4 * 4 + 1) * 64 + lane], h);
        h = fmaf(a.z, W1[(k4 * 4 + 2) * 64 + lane], h);
        h = fmaf(a.w, W1[(k4 * 4 + 3) * 64 + lane], h);
    }
    h = fmaxf(h, 0.f);
    __syncthreads();
    lds[w][lane] = h;
    __syncthreads();
    if (active && lane < 16) {
        float s = 0.f;
        const float4* hr = (const float4*)lds[w];
#pragma unroll
        for (int j4 = 0; j4 < 16; ++j4) {
            float4 a = hr[j4];
            s = fmaf(a.x, W2[(j4 * 4 + 0) * 16 + lane], s);
            s = fmaf(a.y, W2[(j4 * 4 + 1) * 16 + lane], s);
            s = fmaf(a.z, W2[(j4 * 4 + 2) * 16 + lane], s);
            s = fmaf(a.w, W2[(j4 * 4 + 3) * 16 + lane], s);
        }
        p[(size_t)node * 16 + lane] = s;
    }
}

// ---------- layer 2: wave/node, float2 per lane, 8 edges per load instr ----------
__global__ __launch_bounds__(256) void layer2_kernel(
    const float2* __restrict__ p2, const int* __restrict__ offs,
    const int* __restrict__ ssort, const float* __restrict__ b2,
    float* __restrict__ out, int n_nodes)
{
    int lane = threadIdx.x & 63;
    int w = threadIdx.x >> 6;
    int node = blockIdx.x * 4 + w;
    if (node >= n_nodes) return;
    int slot = lane >> 3;   // edge slot 0..7
    int cp = lane & 7;      // column pair -> cols 2cp, 2cp+1
    int beg = offs[node], end = offs[node + 1];
    float ax = 0.f, ay = 0.f;
    int k = beg + slot;
    for (; k + 8 < end; k += 16) {      // 2-way unroll: 16 edges in flight
        int s0 = ssort[k], s1 = ssort[k + 8];
        float2 v0 = p2[(size_t)s0 * 8 + cp];
        float2 v1 = p2[(size_t)s1 * 8 + cp];
        ax += v0.x + v1.x;
        ay += v0.y + v1.y;
    }
    for (; k < end; k += 8) {
        float2 v = p2[(size_t)ssort[k] * 8 + cp];
        ax += v.x;
        ay += v.y;
    }
    // reduce over the 8 edge slots (bits 3..5 of lane)
    ax += __shfl_xor(ax, 8, 64);  ay += __shfl_xor(ay, 8, 64);
    ax += __shfl_xor(ax, 16, 64); ay += __shfl_xor(ay, 16, 64);
    ax += __shfl_xor(ax, 32, 64); ay += __shfl_xor(ay, 32, 64);
    float2 bb = ((const float2*)b2)[cp];
    float vx = ax + bb.x, vy = ay + bb.y;
    // softmax over 16 classes = 8 cp-lanes x 2
    float m = fmaxf(vx, vy);
    m = fmaxf(m, __shfl_xor(m, 1, 64));
    m = fmaxf(m, __shfl_xor(m, 2, 64));
    m = fmaxf(m, __shfl_xor(m, 4, 64));
    float ex = __expf(vx - m), ey = __expf(vy - m);
    float s = ex + ey;
    s += __shfl_xor(s, 1, 64);
    s += __shfl_xor(s, 2, 64);
    s += __shfl_xor(s, 4, 64);
    if (slot == 0) {
        float inv = 1.f / s;
        float2 o; o.x = ex * inv; o.y = ey * inv;
        ((float2*)out)[(size_t)node * 8 + cp] = o;
    }
}

extern "C" void kernel_launch(void* const* d_in, const int* in_sizes, int n_in,
                              void* d_out, int out_size, void* d_ws, size_t ws_size,
                              hipStream_t stream) {
    const float* feat = (const float*)d_in[0];
    const float* W1   = (const float*)d_in[1];
    const float* b1   = (const float*)d_in[2];
    const float* W2   = (const float*)d_in[3];
    const float* b2   = (const float*)d_in[4];
    const int*   src  = (const int*)d_in[5];
    const int*   dst  = (const int*)d_in[6];

    int N = in_sizes[0] / 64;
    int E = in_sizes[5];

    // workspace layout
    float*    p      = (float*)d_ws;                         // N*16 f32
    unsigned* gbf    = (unsigned*)(p + (size_t)N * 16);      // N*32 u32 (bf16 path)
    int*      counts = (int*)(gbf + (size_t)N * 32);         // N
    int*      offs   = counts + N;                           // N+1
    int*      cursor = offs + N + 1;                         // N
    int*      bsums  = cursor + N;                           // SCAN_B
    int*      ssort  = bsums + SCAN_B;                       // E
    size_t need_bf16 = (size_t)(ssort + E - (int*)d_ws) * sizeof(int);
    bool use_bf16 = ws_size >= need_bf16;
    if (!use_bf16) {
        // compact layout without gbf
        counts = (int*)(p + (size_t)N * 16);
        offs   = counts + N;
        cursor = offs + N + 1;
        bsums  = cursor + N;
        ssort  = bsums + SCAN_B;
    }
    float* out = (float*)d_out;

    int nb = (N + SCAN_B - 1) / SCAN_B;

    hipMemsetAsync(counts, 0, (size_t)N * sizeof(int), stream);

    hist_kernel<<<(E + 255) / 256, 256, 0, stream>>>(dst, counts, E);
    if (use_bf16) {
        long n32 = (long)N * 32;
        tobf16_kernel<<<(int)((n32 + 255) / 256), 256, 0, stream>>>((const float2*)feat, gbf, n32);
    }
    scan_phaseA<<<nb, SCAN_B, 0, stream>>>(counts, offs, bsums, N);
    scan_phaseB<<<1, SCAN_B, 0, stream>>>(bsums, nb);
    scan_phaseC<<<(N + 1 + 255) / 256, 256, 0, stream>>>(offs, bsums, cursor, N, E);
    fill_kernel<<<(E + 255) / 256, 256, 0, stream>>>(src, dst, cursor, ssort, E);

    if (use_bf16) {
        layer1_bf16_kernel<<<(N + 3) / 4, 256, 0, stream>>>(gbf, offs, ssort, W1, b1, W2, p, N);
    } else {
        layer1_f32_kernel<<<(N + 3) / 4, 256, 0, stream>>>(feat, offs, ssort, W1, b1, W2, p, N);
    }
    layer2_kernel<<<(N + 3) / 4, 256, 0, stream>>>((const float2*)p, offs, ssort, b2, out, N);
}